// Round 1
// baseline (324.451 us; speedup 1.0000x reference)
//
#include <hip/hip_runtime.h>
#include <math.h>

#define Bb 8
#define Tt 12
#define Nn 512
#define Dd 64
#define NNe 16
#define MS 45
#define BT (Bb*Tt)
#define ROWS (BT*Nn)

static __device__ __forceinline__ float bcast_lane(float v, int e) {
    return __uint_as_float(__builtin_amdgcn_readlane(__float_as_uint(v), e));
}

static __device__ __forceinline__ float wave_sum(float v) {
    for (int off = 32; off; off >>= 1) v += __shfl_xor(v, off, 64);
    return v;
}
static __device__ __forceinline__ float wave_max(float v) {
    for (int off = 32; off; off >>= 1) v = fmaxf(v, __shfl_xor(v, off, 64));
    return v;
}

// ---------------- K1: x_ = x + ev ; Q,K,V = x_ @ W + b -------------------
__global__ __launch_bounds__(256) void k_qkv(
    const float* __restrict__ x, const float* __restrict__ eigvec,
    const float* __restrict__ eigvalue,
    const float* __restrict__ Wq, const float* __restrict__ bq,
    const float* __restrict__ Wk, const float* __restrict__ bk,
    const float* __restrict__ Wv, const float* __restrict__ bv,
    float* __restrict__ xw, float* __restrict__ Qo,
    float* __restrict__ Ko, float* __restrict__ Vo)
{
    __shared__ float sWq[Dd*Dd], sWk[Dd*Dd], sWv[Dd*Dd];
    for (int i = threadIdx.x; i < Dd*Dd; i += 256) {
        sWq[i] = Wq[i]; sWk[i] = Wk[i]; sWv[i] = Wv[i];
    }
    __syncthreads();
    const int wave = threadIdx.x >> 6, lane = threadIdx.x & 63;
    const int base = (blockIdx.x * 4 + wave) * 4;   // 4 rows per wave
    const float evl = eigvalue[lane];

    float xs[4];
    #pragma unroll
    for (int r = 0; r < 4; ++r) {
        int row = base + r;
        int n = row & (Nn - 1);
        float v = x[(size_t)row*Dd + lane] + eigvec[lane*Nn + n] * evl;
        xs[r] = v;
        xw[(size_t)row*Dd + lane] = v;
    }
    float q[4], k[4], vv[4];
    #pragma unroll
    for (int r = 0; r < 4; ++r) { q[r] = bq[lane]; k[r] = bk[lane]; vv[r] = bv[lane]; }

    for (int e = 0; e < Dd; ++e) {
        float wq = sWq[e*Dd + lane], wk = sWk[e*Dd + lane], wv = sWv[e*Dd + lane];
        #pragma unroll
        for (int r = 0; r < 4; ++r) {
            float xe = bcast_lane(xs[r], e);
            q[r]  += xe * wq;
            k[r]  += xe * wk;
            vv[r] += xe * wv;
        }
    }
    #pragma unroll
    for (int r = 0; r < 4; ++r) {
        size_t off = (size_t)(base + r)*Dd + lane;
        Qo[off] = q[r]; Ko[off] = k[r]; Vo[off] = vv[r];
    }
}

// ---------------- K2: qk (adj gather), gat, M ----------------------------
__global__ __launch_bounds__(256) void k_gatM(
    const float* __restrict__ Q, const float* __restrict__ K,
    const float* __restrict__ V, const int* __restrict__ adj,
    const float* __restrict__ Wp, const float* __restrict__ bp,
    float* __restrict__ Mout)
{
    const int gw = blockIdx.x * 4 + (threadIdx.x >> 6);
    const int lane = threadIdx.x & 63;
    const int row = gw;
    const int bt = row >> 9, n = row & (Nn - 1);
    const float q = Q[(size_t)row*Dd + lane];
    const float* Kbt = K + (size_t)bt*Nn*Dd;
    const float* Vbt = V + (size_t)bt*Nn*Dd;
    float gat = 0.f;
    #pragma unroll 4
    for (int kk = 0; kk < NNe; ++kk) {
        int j = adj[n*NNe + kk];
        float p = wave_sum(q * Kbt[j*Dd + lane]);
        gat += p * Vbt[j*Dd + lane];
    }
    float m = wave_sum(gat * Wp[lane]);
    if (lane == 0) Mout[row] = m + bp[0];
}

// ---------------- K3: top-45 per (b,t), jax.lax.top_k semantics ----------
__global__ __launch_bounds__(512) void k_topk(
    const float* __restrict__ Mv, int* __restrict__ Mtop)
{
    __shared__ float sv[Nn];
    __shared__ float rv[Nn];
    __shared__ int   ri[Nn];
    const int bt = blockIdx.x, t = threadIdx.x;
    sv[t] = Mv[bt*Nn + t];
    __syncthreads();
    for (int s = 0; s < MS; ++s) {
        rv[t] = sv[t]; ri[t] = t;
        __syncthreads();
        for (int off = 256; off; off >>= 1) {
            if (t < off) {
                float v2 = rv[t+off]; int i2 = ri[t+off];
                if (v2 > rv[t] || (v2 == rv[t] && i2 < ri[t])) { rv[t] = v2; ri[t] = i2; }
            }
            __syncthreads();
        }
        int w = ri[0];
        if (t == 0) Mtop[bt*MS + s] = w;
        if (t == w) sv[t] = -INFINITY;
        __syncthreads();
    }
}

// ---------------- K4: scores = Q_red @ K^T / 8 ---------------------------
// block = (bt, 128-n chunk); K chunk transposed in LDS: sK[e][nloc] pad 132
__global__ __launch_bounds__(256) void k_scores(
    const float* __restrict__ Q, const float* __restrict__ K,
    const int* __restrict__ Mtop, float* __restrict__ attn)
{
    __shared__ __attribute__((aligned(16))) float sK[Dd*132];
    __shared__ __attribute__((aligned(16))) float sQ[MS*Dd];
    const int bt = blockIdx.x >> 2;
    const int n0 = (blockIdx.x & 3) * 128;
    const float* Kbt = K + (size_t)bt*Nn*Dd;
    const float* Qbt = Q + (size_t)bt*Nn*Dd;
    for (int i = threadIdx.x; i < 128*Dd; i += 256) {
        int nloc = i >> 6, e = i & 63;
        sK[e*132 + nloc] = Kbt[(n0 + nloc)*Dd + e];
    }
    for (int i = threadIdx.x; i < MS*Dd; i += 256) {
        int m = i >> 6, e = i & 63;
        sQ[i] = Qbt[(size_t)Mtop[bt*MS + m]*Dd + e];
    }
    __syncthreads();
    // 3m x 4n register tiles: 15 m-groups * 32 n-groups = 480 tiles
    for (int tile = threadIdx.x; tile < 480; tile += 256) {
        const int m0 = (tile >> 5) * 3;
        const int ng = (tile & 31) * 4;
        float ax[3][4] = {};
        for (int e = 0; e < Dd; ++e) {
            const float4 kv = *reinterpret_cast<const float4*>(&sK[e*132 + ng]);
            #pragma unroll
            for (int i = 0; i < 3; ++i) {
                float qv = sQ[(m0 + i)*Dd + e];
                ax[i][0] += qv * kv.x; ax[i][1] += qv * kv.y;
                ax[i][2] += qv * kv.z; ax[i][3] += qv * kv.w;
            }
        }
        #pragma unroll
        for (int i = 0; i < 3; ++i) {
            float4 o;
            o.x = ax[i][0]*0.125f; o.y = ax[i][1]*0.125f;
            o.z = ax[i][2]*0.125f; o.w = ax[i][3]*0.125f;
            *reinterpret_cast<float4*>(
                &attn[((size_t)bt*MS + m0 + i)*Nn + n0 + ng]) = o;
        }
    }
}

// ---------------- K5: softmax over n (512) per (bt,m) row ----------------
__global__ __launch_bounds__(256) void k_softmax(float* __restrict__ attn)
{
    const int gw = blockIdx.x * 4 + (threadIdx.x >> 6);
    const int lane = threadIdx.x & 63;
    if (gw >= BT*MS) return;
    float* row = attn + (size_t)gw*Nn;
    float v[8];
    float mx = -INFINITY;
    #pragma unroll
    for (int i = 0; i < 8; ++i) { v[i] = row[i*64 + lane]; mx = fmaxf(mx, v[i]); }
    mx = wave_max(mx);
    float sum = 0.f;
    #pragma unroll
    for (int i = 0; i < 8; ++i) { v[i] = expf(v[i] - mx); sum += v[i]; }
    sum = wave_sum(sum);
    float inv = 1.f / sum;
    #pragma unroll
    for (int i = 0; i < 8; ++i) row[i*64 + lane] = v[i] * inv;
}

// ---------------- K6: av = attn @ V  (5 m per wave) ----------------------
__global__ __launch_bounds__(256) void k_av(
    const float* __restrict__ attn, const float* __restrict__ V,
    float* __restrict__ av)
{
    const int gw = blockIdx.x * 4 + (threadIdx.x >> 6);
    const int lane = threadIdx.x & 63;
    if (gw >= BT*9) return;
    const int bt = gw / 9, m0 = (gw % 9) * 5;
    const float* a0 = attn + ((size_t)bt*MS + m0)*Nn;
    const float* Vbt = V + (size_t)bt*Nn*Dd;
    float acc[5] = {0,0,0,0,0};
    for (int n = 0; n < Nn; ++n) {
        float v = Vbt[n*Dd + lane];
        #pragma unroll
        for (int i = 0; i < 5; ++i) acc[i] += a0[(size_t)i*Nn + n] * v;
    }
    #pragma unroll
    for (int i = 0; i < 5; ++i)
        av[((size_t)bt*MS + m0 + i)*Dd + lane] = acc[i];
}

// ---------------- K7: cp = argmax over m of attn[:,n] (first max) --------
__global__ __launch_bounds__(256) void k_cp(
    const float* __restrict__ attn, int* __restrict__ cp)
{
    const int t = blockIdx.x * 256 + threadIdx.x;
    const int bt = t >> 9, n = t & (Nn - 1);
    const float* a = attn + (size_t)bt*MS*Nn + n;
    float best = a[0]; int bi = 0;
    for (int m = 1; m < MS; ++m) {
        float v = a[(size_t)m*Nn];
        if (v > best) { best = v; bi = m; }
    }
    cp[t] = bi;
}

// ---------------- K8: gather + Wo + residual + LN + FFN + LN -------------
__global__ __launch_bounds__(256) void k_final(
    const float* __restrict__ av, const int* __restrict__ cp,
    const float* __restrict__ xw,
    const float* __restrict__ Wo, const float* __restrict__ bo,
    const float* __restrict__ W1, const float* __restrict__ b1,
    const float* __restrict__ W2, const float* __restrict__ b2,
    float* __restrict__ out)
{
    __shared__ float sWo[Dd*Dd], sW1[Dd*Dd], sW2[Dd*Dd];
    for (int i = threadIdx.x; i < Dd*Dd; i += 256) {
        sWo[i] = Wo[i]; sW1[i] = W1[i]; sW2[i] = W2[i];
    }
    __syncthreads();
    const int wave = threadIdx.x >> 6, lane = threadIdx.x & 63;
    const int base = (blockIdx.x * 4 + wave) * 4;
    const int bt = base >> 9;

    // stage 1: g = av[cp[row]] ; o = g @ Wo + bo + x_
    float g[4], o[4];
    #pragma unroll
    for (int r = 0; r < 4; ++r) {
        int c = cp[base + r];
        g[r] = av[((size_t)bt*MS + c)*Dd + lane];
        o[r] = bo[lane] + xw[(size_t)(base + r)*Dd + lane];
    }
    for (int e = 0; e < Dd; ++e) {
        float w = sWo[e*Dd + lane];
        #pragma unroll
        for (int r = 0; r < 4; ++r) o[r] += bcast_lane(g[r], e) * w;
    }
    // LN1
    float val[4];
    #pragma unroll
    for (int r = 0; r < 4; ++r) {
        float mu = wave_sum(o[r]) * (1.f/64.f);
        float d  = o[r] - mu;
        float vs = wave_sum(d*d) * (1.f/64.f);
        val[r] = d * rsqrtf(vs + 1e-5f);
    }
    // FFN layer 1
    float u[4];
    #pragma unroll
    for (int r = 0; r < 4; ++r) u[r] = b1[lane];
    for (int e = 0; e < Dd; ++e) {
        float w = sW1[e*Dd + lane];
        #pragma unroll
        for (int r = 0; r < 4; ++r) u[r] += bcast_lane(val[r], e) * w;
    }
    #pragma unroll
    for (int r = 0; r < 4; ++r) u[r] = fmaxf(u[r], 0.f);
    // FFN layer 2
    float h[4];
    #pragma unroll
    for (int r = 0; r < 4; ++r) h[r] = b2[lane];
    for (int e = 0; e < Dd; ++e) {
        float w = sW2[e*Dd + lane];
        #pragma unroll
        for (int r = 0; r < 4; ++r) h[r] += bcast_lane(u[r], e) * w;
    }
    // LN2 + store
    #pragma unroll
    for (int r = 0; r < 4; ++r) {
        float x2 = h[r] + val[r];
        float mu = wave_sum(x2) * (1.f/64.f);
        float d  = x2 - mu;
        float vs = wave_sum(d*d) * (1.f/64.f);
        out[(size_t)(base + r)*Dd + lane] = d * rsqrtf(vs + 1e-5f);
    }
}

extern "C" void kernel_launch(void* const* d_in, const int* in_sizes, int n_in,
                              void* d_out, int out_size, void* d_ws, size_t ws_size,
                              hipStream_t stream)
{
    const float* x        = (const float*)d_in[0];
    const int*   adj      = (const int*)  d_in[1];
    const float* eigvec   = (const float*)d_in[2];
    const float* eigvalue = (const float*)d_in[3];
    const float* Wq = (const float*)d_in[4],  *bq = (const float*)d_in[5];
    const float* Wk = (const float*)d_in[6],  *bk = (const float*)d_in[7];
    const float* Wv = (const float*)d_in[8],  *bv = (const float*)d_in[9];
    const float* Wo = (const float*)d_in[10], *bo = (const float*)d_in[11];
    const float* Wp = (const float*)d_in[12], *bp = (const float*)d_in[13];
    const float* W1 = (const float*)d_in[14], *b1 = (const float*)d_in[15];
    const float* W2 = (const float*)d_in[16], *b2 = (const float*)d_in[17];

    const size_t RD = (size_t)ROWS * Dd;
    float* ws   = (float*)d_ws;
    float* Q    = ws;
    float* K    = Q + RD;
    float* V    = K + RD;
    float* Mv   = V + RD;
    float* attn = Mv + ROWS;
    float* av   = attn + (size_t)BT*MS*Nn;
    int*   Mtop = (int*)(av + (size_t)BT*MS*Dd);
    int*   cp   = Mtop + BT*MS;
    float* xw   = (float*)d_out;   // aliased: k_final reads xw[row] before writing out[row]
    float* out  = (float*)d_out;

    k_qkv   <<<ROWS/16, 256, 0, stream>>>(x, eigvec, eigvalue, Wq,bq, Wk,bk, Wv,bv, xw, Q, K, V);
    k_gatM  <<<ROWS/4,  256, 0, stream>>>(Q, K, V, adj, Wp, bp, Mv);
    k_topk  <<<BT,      512, 0, stream>>>(Mv, Mtop);
    k_scores<<<BT*4,    256, 0, stream>>>(Q, K, Mtop, attn);
    k_softmax<<<(BT*MS)/4, 256, 0, stream>>>(attn);
    k_av    <<<(BT*9)/4, 256, 0, stream>>>(attn, V, av);
    k_cp    <<<ROWS/256, 256, 0, stream>>>(attn, cp);
    k_final <<<ROWS/16, 256, 0, stream>>>(av, cp, xw, Wo,bo, W1,b1, W2,b2, out);
}

// Round 2
// 273.337 us; speedup vs baseline: 1.1870x; 1.1870x over previous
//
#include <hip/hip_runtime.h>
#include <math.h>

#define Bb 8
#define Tt 12
#define Nn 512
#define Dd 64
#define NNe 16
#define MS 45
#define BT (Bb*Tt)
#define ROWS (BT*Nn)

static __device__ __forceinline__ float bcast_lane(float v, int e) {
    return __uint_as_float(__builtin_amdgcn_readlane(__float_as_uint(v), e));
}

static __device__ __forceinline__ float wave_sum(float v) {
    for (int off = 32; off; off >>= 1) v += __shfl_xor(v, off, 64);
    return v;
}
static __device__ __forceinline__ float wave_max(float v) {
    for (int off = 32; off; off >>= 1) v = fmaxf(v, __shfl_xor(v, off, 64));
    return v;
}

// ---------------- K0: evT[n][d] = eigvec[d][n] * eigvalue[d] -------------
__global__ __launch_bounds__(256) void k_evT(
    const float* __restrict__ eigvec, const float* __restrict__ eigvalue,
    float* __restrict__ evT)
{
    const int i = blockIdx.x * 256 + threadIdx.x;   // i over D*N, d-major
    const int d = i >> 9, n = i & (Nn - 1);
    evT[n*Dd + d] = eigvec[i] * eigvalue[d];        // read coalesced, write strided (one-shot, 128KB)
}

// ---------------- K1: x_ = x + ev ; Q,K,V = x_ @ W + b ; pv = V·Wp -------
__global__ __launch_bounds__(256) void k_qkv(
    const float* __restrict__ x, const float* __restrict__ evT,
    const float* __restrict__ Wq, const float* __restrict__ bq,
    const float* __restrict__ Wk, const float* __restrict__ bk,
    const float* __restrict__ Wv, const float* __restrict__ bv,
    const float* __restrict__ Wp,
    float* __restrict__ xw, float* __restrict__ Qo,
    float* __restrict__ Ko, float* __restrict__ Vo, float* __restrict__ pv)
{
    __shared__ float sWq[Dd*Dd], sWk[Dd*Dd], sWv[Dd*Dd];
    for (int i = threadIdx.x; i < Dd*Dd; i += 256) {
        sWq[i] = Wq[i]; sWk[i] = Wk[i]; sWv[i] = Wv[i];
    }
    __syncthreads();
    const int wave = threadIdx.x >> 6, lane = threadIdx.x & 63;
    const int base = (blockIdx.x * 4 + wave) * 4;   // 4 rows per wave

    float xs[4];
    #pragma unroll
    for (int r = 0; r < 4; ++r) {
        int row = base + r;
        int n = row & (Nn - 1);
        float v = x[(size_t)row*Dd + lane] + evT[n*Dd + lane];
        xs[r] = v;
        xw[(size_t)row*Dd + lane] = v;
    }
    float q[4], k[4], vv[4];
    #pragma unroll
    for (int r = 0; r < 4; ++r) { q[r] = bq[lane]; k[r] = bk[lane]; vv[r] = bv[lane]; }

    for (int e = 0; e < Dd; ++e) {
        float wq = sWq[e*Dd + lane], wk = sWk[e*Dd + lane], wv = sWv[e*Dd + lane];
        #pragma unroll
        for (int r = 0; r < 4; ++r) {
            float xe = bcast_lane(xs[r], e);
            q[r]  += xe * wq;
            k[r]  += xe * wk;
            vv[r] += xe * wv;
        }
    }
    const float wp = Wp[lane];
    #pragma unroll
    for (int r = 0; r < 4; ++r) {
        size_t off = (size_t)(base + r)*Dd + lane;
        Qo[off] = q[r]; Ko[off] = k[r]; Vo[off] = vv[r];
        float p = wave_sum(vv[r] * wp);
        if (lane == 0) pv[base + r] = p;
    }
}

// ---------------- K2: M[n] = bp + sum_k (Q[n]·K[adj])·pv[adj] ------------
// One block per (bt, half). K[bt] staged in LDS, XOR-swizzled in float4
// units so random-j gathers spread evenly over bank-quads.
__global__ __launch_bounds__(256) void k_M(
    const float* __restrict__ Q, const float* __restrict__ K,
    const int* __restrict__ adj, const float* __restrict__ pv,
    const float* __restrict__ bp, float* __restrict__ Mout)
{
    __shared__ __attribute__((aligned(16))) float sK[Nn*Dd];  // 128 KB
    const int bt = blockIdx.x >> 1;
    const int half = blockIdx.x & 1;

    const float4* Ksrc = reinterpret_cast<const float4*>(K + (size_t)bt*Nn*Dd);
    float4* sK4 = reinterpret_cast<float4*>(sK);
    for (int i4 = threadIdx.x; i4 < Nn*16; i4 += 256) {
        int nn = i4 >> 4, e4 = i4 & 15;
        sK4[(nn << 4) | (e4 ^ (nn & 15))] = Ksrc[i4];
    }
    __syncthreads();

    const int n = half*256 + threadIdx.x;
    float4 q4[16];
    const float4* Qr = reinterpret_cast<const float4*>(Q + ((size_t)bt*Nn + n)*Dd);
    #pragma unroll
    for (int i = 0; i < 16; ++i) q4[i] = Qr[i];

    const float* pvbt = pv + (size_t)bt*Nn;
    float m = bp[0];
    #pragma unroll 1
    for (int k = 0; k < NNe; ++k) {
        const int j = adj[(n << 4) + k];
        const float4* kr = sK4 + ((size_t)j << 4);
        const int sw = j & 15;
        float dot = 0.f;
        #pragma unroll
        for (int e4 = 0; e4 < 16; ++e4) {
            float4 kv = kr[e4 ^ sw];
            dot += q4[e4].x*kv.x + q4[e4].y*kv.y + q4[e4].z*kv.z + q4[e4].w*kv.w;
        }
        m += dot * pvbt[j];
    }
    Mout[bt*Nn + n] = m;
}

// ---------------- K3: top-45 per (b,t): one wave per bt, shuffle argmax --
__global__ __launch_bounds__(256) void k_topk(
    const float* __restrict__ Mv, int* __restrict__ Mtop)
{
    const int bt = blockIdx.x * 4 + (threadIdx.x >> 6);
    const int lane = threadIdx.x & 63;
    float v[8];
    #pragma unroll
    for (int i = 0; i < 8; ++i) v[i] = Mv[bt*Nn + i*64 + lane];
    for (int s = 0; s < MS; ++s) {
        float bv = v[0]; int bn = lane;
        #pragma unroll
        for (int i = 1; i < 8; ++i) {
            int nn = i*64 + lane;
            if (v[i] > bv) { bv = v[i]; bn = nn; }   // later nn always larger: > keeps min idx
        }
        for (int off = 32; off; off >>= 1) {
            float ov = __shfl_xor(bv, off, 64);
            int   on = __shfl_xor(bn, off, 64);
            if (ov > bv || (ov == bv && on < bn)) { bv = ov; bn = on; }
        }
        if (lane == 0) Mtop[bt*MS + s] = bn;
        const int wl = bn & 63, wi = bn >> 6;
        if (lane == wl) {
            #pragma unroll
            for (int i = 0; i < 8; ++i) if (i == wi) v[i] = -INFINITY;
        }
    }
}

// ---------------- K4: scores = Q_red @ K^T / 8 ---------------------------
__global__ __launch_bounds__(256) void k_scores(
    const float* __restrict__ Q, const float* __restrict__ K,
    const int* __restrict__ Mtop, float* __restrict__ attn)
{
    __shared__ __attribute__((aligned(16))) float sK[Dd*132];
    __shared__ __attribute__((aligned(16))) float sQ[MS*Dd];
    const int bt = blockIdx.x >> 2;
    const int n0 = (blockIdx.x & 3) * 128;
    const float* Kbt = K + (size_t)bt*Nn*Dd;
    const float* Qbt = Q + (size_t)bt*Nn*Dd;
    for (int i = threadIdx.x; i < 128*Dd; i += 256) {
        int nloc = i >> 6, e = i & 63;
        sK[e*132 + nloc] = Kbt[(n0 + nloc)*Dd + e];
    }
    for (int i = threadIdx.x; i < MS*Dd; i += 256) {
        int m = i >> 6, e = i & 63;
        sQ[i] = Qbt[(size_t)Mtop[bt*MS + m]*Dd + e];
    }
    __syncthreads();
    for (int tile = threadIdx.x; tile < 480; tile += 256) {
        const int m0 = (tile >> 5) * 3;
        const int ng = (tile & 31) * 4;
        float ax[3][4] = {};
        for (int e = 0; e < Dd; ++e) {
            const float4 kv = *reinterpret_cast<const float4*>(&sK[e*132 + ng]);
            #pragma unroll
            for (int i = 0; i < 3; ++i) {
                float qv = sQ[(m0 + i)*Dd + e];
                ax[i][0] += qv * kv.x; ax[i][1] += qv * kv.y;
                ax[i][2] += qv * kv.z; ax[i][3] += qv * kv.w;
            }
        }
        #pragma unroll
        for (int i = 0; i < 3; ++i) {
            float4 o;
            o.x = ax[i][0]*0.125f; o.y = ax[i][1]*0.125f;
            o.z = ax[i][2]*0.125f; o.w = ax[i][3]*0.125f;
            *reinterpret_cast<float4*>(
                &attn[((size_t)bt*MS + m0 + i)*Nn + n0 + ng]) = o;
        }
    }
}

// ---------------- K5: softmax over n (512) per (bt,m) row ----------------
__global__ __launch_bounds__(256) void k_softmax(float* __restrict__ attn)
{
    const int gw = blockIdx.x * 4 + (threadIdx.x >> 6);
    const int lane = threadIdx.x & 63;
    if (gw >= BT*MS) return;
    float* row = attn + (size_t)gw*Nn;
    float v[8];
    float mx = -INFINITY;
    #pragma unroll
    for (int i = 0; i < 8; ++i) { v[i] = row[i*64 + lane]; mx = fmaxf(mx, v[i]); }
    mx = wave_max(mx);
    float sum = 0.f;
    #pragma unroll
    for (int i = 0; i < 8; ++i) { v[i] = expf(v[i] - mx); sum += v[i]; }
    sum = wave_sum(sum);
    float inv = 1.f / sum;
    #pragma unroll
    for (int i = 0; i < 8; ++i) row[i*64 + lane] = v[i] * inv;
}

// ---------------- K6: av = attn @ V  (5 m per wave) ----------------------
__global__ __launch_bounds__(256) void k_av(
    const float* __restrict__ attn, const float* __restrict__ V,
    float* __restrict__ av)
{
    const int gw = blockIdx.x * 4 + (threadIdx.x >> 6);
    const int lane = threadIdx.x & 63;
    if (gw >= BT*9) return;
    const int bt = gw / 9, m0 = (gw % 9) * 5;
    const float* a0 = attn + ((size_t)bt*MS + m0)*Nn;
    const float* Vbt = V + (size_t)bt*Nn*Dd;
    float acc[5] = {0,0,0,0,0};
    for (int n = 0; n < Nn; ++n) {
        float v = Vbt[n*Dd + lane];
        #pragma unroll
        for (int i = 0; i < 5; ++i) acc[i] += a0[(size_t)i*Nn + n] * v;
    }
    #pragma unroll
    for (int i = 0; i < 5; ++i)
        av[((size_t)bt*MS + m0 + i)*Dd + lane] = acc[i];
}

// ---------------- K7: cp = argmax over m of attn[:,n] (first max) --------
__global__ __launch_bounds__(256) void k_cp(
    const float* __restrict__ attn, int* __restrict__ cp)
{
    const int t = blockIdx.x * 256 + threadIdx.x;
    const int bt = t >> 9, n = t & (Nn - 1);
    const float* a = attn + (size_t)bt*MS*Nn + n;
    float best = a[0]; int bi = 0;
    for (int m = 1; m < MS; ++m) {
        float v = a[(size_t)m*Nn];
        if (v > best) { best = v; bi = m; }
    }
    cp[t] = bi;
}

// ---------------- K8: gather + Wo + residual + LN + FFN + LN -------------
__global__ __launch_bounds__(256) void k_final(
    const float* __restrict__ av, const int* __restrict__ cp,
    const float* __restrict__ xw,
    const float* __restrict__ Wo, const float* __restrict__ bo,
    const float* __restrict__ W1, const float* __restrict__ b1,
    const float* __restrict__ W2, const float* __restrict__ b2,
    float* __restrict__ out)
{
    __shared__ float sWo[Dd*Dd], sW1[Dd*Dd], sW2[Dd*Dd];
    for (int i = threadIdx.x; i < Dd*Dd; i += 256) {
        sWo[i] = Wo[i]; sW1[i] = W1[i]; sW2[i] = W2[i];
    }
    __syncthreads();
    const int wave = threadIdx.x >> 6, lane = threadIdx.x & 63;
    const int base = (blockIdx.x * 4 + wave) * 4;
    const int bt = base >> 9;

    float g[4], o[4];
    #pragma unroll
    for (int r = 0; r < 4; ++r) {
        int c = cp[base + r];
        g[r] = av[((size_t)bt*MS + c)*Dd + lane];
        o[r] = bo[lane] + xw[(size_t)(base + r)*Dd + lane];
    }
    for (int e = 0; e < Dd; ++e) {
        float w = sWo[e*Dd + lane];
        #pragma unroll
        for (int r = 0; r < 4; ++r) o[r] += bcast_lane(g[r], e) * w;
    }
    float val[4];
    #pragma unroll
    for (int r = 0; r < 4; ++r) {
        float mu = wave_sum(o[r]) * (1.f/64.f);
        float d  = o[r] - mu;
        float vs = wave_sum(d*d) * (1.f/64.f);
        val[r] = d * rsqrtf(vs + 1e-5f);
    }
    float u[4];
    #pragma unroll
    for (int r = 0; r < 4; ++r) u[r] = b1[lane];
    for (int e = 0; e < Dd; ++e) {
        float w = sW1[e*Dd + lane];
        #pragma unroll
        for (int r = 0; r < 4; ++r) u[r] += bcast_lane(val[r], e) * w;
    }
    #pragma unroll
    for (int r = 0; r < 4; ++r) u[r] = fmaxf(u[r], 0.f);
    float h[4];
    #pragma unroll
    for (int r = 0; r < 4; ++r) h[r] = b2[lane];
    for (int e = 0; e < Dd; ++e) {
        float w = sW2[e*Dd + lane];
        #pragma unroll
        for (int r = 0; r < 4; ++r) h[r] += bcast_lane(u[r], e) * w;
    }
    #pragma unroll
    for (int r = 0; r < 4; ++r) {
        float x2 = h[r] + val[r];
        float mu = wave_sum(x2) * (1.f/64.f);
        float d  = x2 - mu;
        float vs = wave_sum(d*d) * (1.f/64.f);
        out[(size_t)(base + r)*Dd + lane] = d * rsqrtf(vs + 1e-5f);
    }
}

extern "C" void kernel_launch(void* const* d_in, const int* in_sizes, int n_in,
                              void* d_out, int out_size, void* d_ws, size_t ws_size,
                              hipStream_t stream)
{
    const float* x        = (const float*)d_in[0];
    const int*   adj      = (const int*)  d_in[1];
    const float* eigvec   = (const float*)d_in[2];
    const float* eigvalue = (const float*)d_in[3];
    const float* Wq = (const float*)d_in[4],  *bq = (const float*)d_in[5];
    const float* Wk = (const float*)d_in[6],  *bk = (const float*)d_in[7];
    const float* Wv = (const float*)d_in[8],  *bv = (const float*)d_in[9];
    const float* Wo = (const float*)d_in[10], *bo = (const float*)d_in[11];
    const float* Wp = (const float*)d_in[12], *bp = (const float*)d_in[13];
    const float* W1 = (const float*)d_in[14], *b1 = (const float*)d_in[15];
    const float* W2 = (const float*)d_in[16], *b2 = (const float*)d_in[17];

    const size_t RD = (size_t)ROWS * Dd;
    float* ws   = (float*)d_ws;
    float* Q    = ws;
    float* K    = Q + RD;
    float* V    = K + RD;
    float* Mv   = V + RD;
    float* attn = Mv + ROWS;
    float* av   = attn + (size_t)BT*MS*Nn;
    float* pv   = av + (size_t)BT*MS*Dd;
    float* evT  = pv + ROWS;
    int*   Mtop = (int*)(evT + Nn*Dd);
    int*   cp   = Mtop + BT*MS;
    float* xw   = (float*)d_out;   // aliased: k_final reads xw[row] before writing out[row]
    float* out  = (float*)d_out;

    k_evT   <<<(Dd*Nn)/256, 256, 0, stream>>>(eigvec, eigvalue, evT);
    k_qkv   <<<ROWS/16, 256, 0, stream>>>(x, evT, Wq,bq, Wk,bk, Wv,bv, Wp, xw, Q, K, V, pv);
    k_M     <<<BT*2,    256, 0, stream>>>(Q, K, adj, pv, bp, Mv);
    k_topk  <<<BT/4,    256, 0, stream>>>(Mv, Mtop);
    k_scores<<<BT*4,    256, 0, stream>>>(Q, K, Mtop, attn);
    k_softmax<<<(BT*MS)/4, 256, 0, stream>>>(attn);
    k_av    <<<(BT*9)/4, 256, 0, stream>>>(attn, V, av);
    k_cp    <<<ROWS/256, 256, 0, stream>>>(attn, cp);
    k_final <<<ROWS/16, 256, 0, stream>>>(av, cp, xw, Wo,bo, W1,b1, W2,b2, out);
}